// Round 1
// baseline (1626.397 us; speedup 1.0000x reference)
//
#include <hip/hip_runtime.h>
#include <math.h>

#define NN 50000
#define NE 800000
#define GG 64
#define MAXDEG 96
#define ATT_SCALE 0.25f   // 1/sqrt(16)

// ---------------- small prep kernels ----------------

__global__ __launch_bounds__(256) void k_count(const int* __restrict__ batch,
                                               float* __restrict__ cnt) {
    int n = blockIdx.x * 256 + threadIdx.x;
    if (n < NN) atomicAdd(&cnt[batch[n]], 1.0f);
}

__global__ void k_inv(const float* __restrict__ cnt, float* __restrict__ inv) {
    int g = threadIdx.x;
    if (g < GG) inv[g] = 1.0f / fmaxf(cnt[g], 1.0f);
}

__global__ __launch_bounds__(256) void k_table(const int* __restrict__ dstv,
                                               int* __restrict__ deg,
                                               int* __restrict__ table) {
    int e = blockIdx.x * 256 + threadIdx.x;
    if (e < NE) {
        int d = dstv[e];
        int r = atomicAdd(&deg[d], 1);
        if (r < MAXDEG) table[(size_t)d * MAXDEG + r] = e;
    }
}

// M[l][i][c] = sum_dd Wq[l][i][h*16+dd] * We[l][j][h*16+dd],  c = h*16+j
__global__ __launch_bounds__(256) void k_M(const float* __restrict__ Wq,
                                           const float* __restrict__ We,
                                           float* __restrict__ M) {
    int t = blockIdx.x * 256 + threadIdx.x;
    if (t >= 5 * 64 * 64) return;
    int l = t >> 12, i = (t >> 6) & 63, c = t & 63;
    int hh = c >> 4, j = c & 15;
    const float* wq = Wq + l * 4096 + i * 64 + hh * 16;
    const float* we = We + l * 1024 + j * 64 + hh * 16;
    float acc = 0.f;
#pragma unroll
    for (int dd = 0; dd < 16; ++dd) acc += wq[dd] * we[dd];
    M[t] = acc;
}

// ---------------- fused projections: Q,K,V,Skip (LDS) + QW (global M) ----------------
// block=256 (4 waves), each wave handles 4 nodes; grid = 50000/16 = 3125 (exact)

__global__ __launch_bounds__(256) void k_proj(const float* __restrict__ hsrc,
                                              const float* __restrict__ Wq,
                                              const float* __restrict__ Wk,
                                              const float* __restrict__ Wv,
                                              const float* __restrict__ Wsk,
                                              const float* __restrict__ Mw,
                                              float* __restrict__ Q, float* __restrict__ K,
                                              float* __restrict__ V, float* __restrict__ S,
                                              float* __restrict__ QW) {
    __shared__ float w4[4][4096];   // 64 KB
    int tid = threadIdx.x;
    for (int i = tid; i < 4096; i += 256) {
        w4[0][i] = Wq[i];
        w4[1][i] = Wk[i];
        w4[2][i] = Wv[i];
        w4[3][i] = Wsk[i];
    }
    __syncthreads();

    int lane = tid & 63, wv = tid >> 6;
    int nb = blockIdx.x * 16 + wv * 4;          // 4 consecutive nodes per wave

    float acc[4][5];
#pragma unroll
    for (int i = 0; i < 4; ++i)
#pragma unroll
        for (int m = 0; m < 5; ++m) acc[i][m] = 0.f;

    const float* h0 = hsrc + (size_t)nb * 64;

#pragma unroll 4
    for (int k = 0; k < 64; ++k) {
        float wl0 = w4[0][k * 64 + lane];
        float wl1 = w4[1][k * 64 + lane];
        float wl2 = w4[2][k * 64 + lane];
        float wl3 = w4[3][k * 64 + lane];
        float wm  = Mw[k * 64 + lane];          // 16 KB slice, L1-resident
#pragma unroll
        for (int i = 0; i < 4; ++i) {
            float hv = h0[i * 64 + k];          // wave-uniform broadcast
            acc[i][0] = fmaf(hv, wl0, acc[i][0]);
            acc[i][1] = fmaf(hv, wl1, acc[i][1]);
            acc[i][2] = fmaf(hv, wl2, acc[i][2]);
            acc[i][3] = fmaf(hv, wl3, acc[i][3]);
            acc[i][4] = fmaf(hv, wm,  acc[i][4]);
        }
    }
#pragma unroll
    for (int i = 0; i < 4; ++i) {
        size_t base = (size_t)(nb + i) * 64 + lane;
        Q[base]  = acc[i][0];
        K[base]  = acc[i][1];
        V[base]  = acc[i][2];
        S[base]  = acc[i][3];
        QW[base] = acc[i][4];
    }
}

// ---------------- per-node online-softmax attention + relu + pool ----------------
// block=256 (4 waves), one node per wave; grid = 12500

__global__ __launch_bounds__(256) void k_attn(const float* __restrict__ Q,
                                              const float* __restrict__ K,
                                              const float* __restrict__ V,
                                              const float* __restrict__ S,
                                              const float* __restrict__ QW,
                                              const float* __restrict__ Wel,
                                              const int* __restrict__ srcv,
                                              const float* __restrict__ eattr,
                                              const int* __restrict__ deg,
                                              const int* __restrict__ table,
                                              const int* __restrict__ batch,
                                              const float* __restrict__ inv,
                                              float* __restrict__ Hout,
                                              float* __restrict__ hcat,
                                              int layer) {
    __shared__ float we[16 * 64];   // 4 KB
    int tid = threadIdx.x;
    for (int i = tid; i < 1024; i += 256) we[i] = Wel[i];
    __syncthreads();

    int lane = tid & 63;
    int n = blockIdx.x * 4 + (tid >> 6);
    if (n >= NN) return;

    int dd = lane & 15;     // attr index within head
    int hg = lane >> 4;     // head

    float q  = Q[(size_t)n * 64 + lane];
    float qw = QW[(size_t)n * 64 + lane];
    int dg = deg[n];
    if (dg > MAXDEG) dg = MAXDEG;

    float m = -INFINITY, s = 0.f, av = 0.f, aa = 0.f;
    const int* tb = table + (size_t)n * MAXDEG;

    int e = 0, sn = 0;
    if (dg > 0) { e = tb[0]; sn = srcv[e]; }
    for (int i = 0; i < dg; ++i) {
        int e2 = 0, sn2 = 0;
        if (i + 1 < dg) { e2 = tb[i + 1]; sn2 = srcv[e2]; }   // prefetch next chain
        float at = eattr[(size_t)e * 16 + dd];
        float kk = K[(size_t)sn * 64 + lane];
        float vv = V[(size_t)sn * 64 + lane];
        float p = fmaf(q, kk, qw * at);
        p += __shfl_xor(p, 1, 16);
        p += __shfl_xor(p, 2, 16);
        p += __shfl_xor(p, 4, 16);
        p += __shfl_xor(p, 8, 16);
        float logit = p * ATT_SCALE;
        float mn = fmaxf(m, logit);
        float wold = __expf(m - mn);     // m=-inf first iter -> 0
        float a = __expf(logit - mn);
        s  = fmaf(s, wold, a);
        av = fmaf(av, wold, a * vv);
        aa = fmaf(aa, wold, a * at);
        m = mn;
        e = e2; sn = sn2;
    }

    float rden = 1.0f / (s + 1e-16f);
    // edge-projection part of aggregation: sum_j accA[h][j] * We[j][lane]
    float eagg = 0.f;
#pragma unroll
    for (int j = 0; j < 16; ++j) {
        float aj = __shfl(aa, hg * 16 + j, 64);
        eagg = fmaf(aj, we[j * 64 + lane], eagg);
    }
    float agg = (av + eagg) * rden;
    float hn = fmaxf(agg + S[(size_t)n * 64 + lane], 0.f);
    Hout[(size_t)n * 64 + lane] = hn;

    int g = batch[n];
    atomicAdd(&hcat[g * 320 + layer * 64 + lane], hn * inv[g]);
}

// ---------------- final MLP: one block per graph ----------------

__global__ __launch_bounds__(256) void k_mlp(const float* __restrict__ hcat,
                                             const float* __restrict__ W1,
                                             const float* __restrict__ b1,
                                             const float* __restrict__ W2,
                                             const float* __restrict__ b2,
                                             float* __restrict__ out) {
    __shared__ float hc[320];
    __shared__ float red[256];
    int g = blockIdx.x, tid = threadIdx.x;
    for (int i = tid; i < 320; i += 256) hc[i] = hcat[g * 320 + i];
    __syncthreads();
    float part = 0.f;
    for (int j = tid; j < 320; j += 256) {
        float t = b1[j];
        for (int k = 0; k < 320; ++k) t = fmaf(hc[k], W1[k * 320 + j], t);
        part = fmaf(fmaxf(t, 0.f), W2[j], part);
    }
    red[tid] = part;
    __syncthreads();
    for (int off = 128; off > 0; off >>= 1) {
        if (tid < off) red[tid] += red[tid + off];
        __syncthreads();
    }
    if (tid == 0) out[g] = red[0] + b2[0];
}

// ---------------- launch ----------------

extern "C" void kernel_launch(void* const* d_in, const int* in_sizes, int n_in,
                              void* d_out, int out_size, void* d_ws, size_t ws_size,
                              hipStream_t stream) {
    const float* x     = (const float*)d_in[0];
    const int*   ei    = (const int*)d_in[1];     // [2,E]: src then dst
    const float* eattr = (const float*)d_in[2];
    const int*   batch = (const int*)d_in[3];
    const float* Wq    = (const float*)d_in[4];
    const float* Wk    = (const float*)d_in[5];
    const float* Wv    = (const float*)d_in[6];
    const float* We    = (const float*)d_in[7];
    const float* Wsk   = (const float*)d_in[8];
    const float* W1    = (const float*)d_in[9];
    const float* b1    = (const float*)d_in[10];
    const float* W2    = (const float*)d_in[11];
    const float* b2    = (const float*)d_in[12];
    float* out = (float*)d_out;

    // workspace carve (floats)
    float* ws = (float*)d_ws;
    size_t o = 0;
    float* Q   = ws + o; o += (size_t)NN * 64;
    float* K   = ws + o; o += (size_t)NN * 64;
    float* V   = ws + o; o += (size_t)NN * 64;
    float* S   = ws + o; o += (size_t)NN * 64;
    float* QW  = ws + o; o += (size_t)NN * 64;
    float* Hb  = ws + o; o += (size_t)NN * 64;
    float* Mw  = ws + o; o += 5 * 4096;
    float* cnt = ws + o; o += GG;
    float* inv = ws + o; o += GG;
    float* hcat= ws + o; o += GG * 320;
    int*   deg = (int*)(ws + o);   o += NN;
    int*   table = (int*)(ws + o); o += (size_t)NN * MAXDEG;

    // zero accumulators: cnt, inv, hcat, deg are contiguous
    size_t zbytes = (size_t)(GG + GG + GG * 320 + NN) * 4;
    hipMemsetAsync(cnt, 0, zbytes, stream);

    k_count<<<(NN + 255) / 256, 256, 0, stream>>>(batch, cnt);
    k_inv<<<1, 64, 0, stream>>>(cnt, inv);
    k_table<<<(NE + 255) / 256, 256, 0, stream>>>(ei + NE, deg, table);
    k_M<<<(5 * 4096 + 255) / 256, 256, 0, stream>>>(Wq, We, Mw);

    const float* hsrc = x;
    for (int l = 0; l < 5; ++l) {
        k_proj<<<3125, 256, 0, stream>>>(hsrc,
                                         Wq + l * 4096, Wk + l * 4096,
                                         Wv + l * 4096, Wsk + l * 4096,
                                         Mw + l * 4096,
                                         Q, K, V, S, QW);
        k_attn<<<(NN + 3) / 4, 256, 0, stream>>>(Q, K, V, S, QW,
                                                 We + l * 1024,
                                                 ei, eattr, deg, table,
                                                 batch, inv, Hb, hcat, l);
        hsrc = Hb;
    }
    k_mlp<<<GG, 256, 0, stream>>>(hcat, W1, b1, W2, b2, out);
}

// Round 2
// 1151.282 us; speedup vs baseline: 1.4127x; 1.4127x over previous
//
#include <hip/hip_runtime.h>
#include <math.h>

#define NN 50000
#define NE 800000
#define GG 64
#define MAXDEG 96
#define ATT_SCALE 0.25f   // 1/sqrt(16)

// ---------------- group sizes via binary search (batch is sorted) ----------------

__global__ void k_bounds(const int* __restrict__ batch, float* __restrict__ inv) {
    int g = threadIdx.x;
    if (g >= GG) return;
    int lo = 0, hi = NN;
    while (lo < hi) { int mid = (lo + hi) >> 1; if (batch[mid] < g) lo = mid + 1; else hi = mid; }
    int lb = lo;
    lo = 0; hi = NN;
    int g1 = g + 1;
    while (lo < hi) { int mid = (lo + hi) >> 1; if (batch[mid] < g1) lo = mid + 1; else hi = mid; }
    inv[g] = 1.0f / fmaxf((float)(lo - lb), 1.0f);
}

// ---------------- incoming-edge table ----------------

__global__ __launch_bounds__(256) void k_table(const int* __restrict__ dstv,
                                               int* __restrict__ deg,
                                               int* __restrict__ table) {
    int e = blockIdx.x * 256 + threadIdx.x;
    if (e < NE) {
        int d = dstv[e];
        int r = atomicAdd(&deg[d], 1);
        if (r < MAXDEG) table[(size_t)d * MAXDEG + r] = e;
    }
}

// M[l][i][c] = sum_dd Wq[l][i][h*16+dd] * We[l][j][h*16+dd],  c = h*16+j
__global__ __launch_bounds__(256) void k_M(const float* __restrict__ Wq,
                                           const float* __restrict__ We,
                                           float* __restrict__ M) {
    int t = blockIdx.x * 256 + threadIdx.x;
    if (t >= 5 * 64 * 64) return;
    int l = t >> 12, i = (t >> 6) & 63, c = t & 63;
    int hh = c >> 4, j = c & 15;
    const float* wq = Wq + l * 4096 + i * 64 + hh * 16;
    const float* we = We + l * 1024 + j * 64 + hh * 16;
    float acc = 0.f;
#pragma unroll
    for (int dd = 0; dd < 16; ++dd) acc += wq[dd] * we[dd];
    M[t] = acc;
}

// ---------------- fused projections: Q,K,V,Skip (LDS b128) + QW (L1) ----------------
// block=256 (4 waves), 4 nodes/wave, 16 nodes/block; grid = 3125 exact

__global__ __launch_bounds__(256) void k_proj(const float* __restrict__ hsrc,
                                              const float* __restrict__ Wq,
                                              const float* __restrict__ Wk,
                                              const float* __restrict__ Wv,
                                              const float* __restrict__ Wsk,
                                              const float* __restrict__ Mw,
                                              float* __restrict__ Q, float* __restrict__ K,
                                              float* __restrict__ V, float* __restrict__ S,
                                              float* __restrict__ QW) {
    __shared__ float wT[4096 * 4];   // [k*64+c][m], 64 KB, read as b128
    __shared__ float hT[16 * 64];    // 4 KB node tile
    int tid = threadIdx.x;
    for (int i = tid; i < 4096; i += 256) {
        float4 w = make_float4(Wq[i], Wk[i], Wv[i], Wsk[i]);
        *reinterpret_cast<float4*>(&wT[i * 4]) = w;
    }
    int nb0 = blockIdx.x * 16;
    for (int i = tid; i < 1024; i += 256) hT[i] = hsrc[(size_t)nb0 * 64 + i];
    __syncthreads();

    int lane = tid & 63, wv = tid >> 6;
    float acc[4][5];
#pragma unroll
    for (int i = 0; i < 4; ++i)
#pragma unroll
        for (int m = 0; m < 5; ++m) acc[i][m] = 0.f;

    int hbase = wv * 4 * 64;

    for (int k = 0; k < 64; k += 4) {
        float4 h0 = *reinterpret_cast<const float4*>(&hT[hbase + 0 * 64 + k]);
        float4 h1 = *reinterpret_cast<const float4*>(&hT[hbase + 1 * 64 + k]);
        float4 h2 = *reinterpret_cast<const float4*>(&hT[hbase + 2 * 64 + k]);
        float4 h3 = *reinterpret_cast<const float4*>(&hT[hbase + 3 * 64 + k]);
#pragma unroll
        for (int kk = 0; kk < 4; ++kk) {
            float4 w = *reinterpret_cast<const float4*>(&wT[((k + kk) * 64 + lane) * 4]);
            float wm = Mw[(k + kk) * 64 + lane];
            float hv0 = reinterpret_cast<const float*>(&h0)[kk];
            float hv1 = reinterpret_cast<const float*>(&h1)[kk];
            float hv2 = reinterpret_cast<const float*>(&h2)[kk];
            float hv3 = reinterpret_cast<const float*>(&h3)[kk];
            acc[0][0] = fmaf(hv0, w.x, acc[0][0]);
            acc[0][1] = fmaf(hv0, w.y, acc[0][1]);
            acc[0][2] = fmaf(hv0, w.z, acc[0][2]);
            acc[0][3] = fmaf(hv0, w.w, acc[0][3]);
            acc[0][4] = fmaf(hv0, wm,  acc[0][4]);
            acc[1][0] = fmaf(hv1, w.x, acc[1][0]);
            acc[1][1] = fmaf(hv1, w.y, acc[1][1]);
            acc[1][2] = fmaf(hv1, w.z, acc[1][2]);
            acc[1][3] = fmaf(hv1, w.w, acc[1][3]);
            acc[1][4] = fmaf(hv1, wm,  acc[1][4]);
            acc[2][0] = fmaf(hv2, w.x, acc[2][0]);
            acc[2][1] = fmaf(hv2, w.y, acc[2][1]);
            acc[2][2] = fmaf(hv2, w.z, acc[2][2]);
            acc[2][3] = fmaf(hv2, w.w, acc[2][3]);
            acc[2][4] = fmaf(hv2, wm,  acc[2][4]);
            acc[3][0] = fmaf(hv3, w.x, acc[3][0]);
            acc[3][1] = fmaf(hv3, w.y, acc[3][1]);
            acc[3][2] = fmaf(hv3, w.z, acc[3][2]);
            acc[3][3] = fmaf(hv3, w.w, acc[3][3]);
            acc[3][4] = fmaf(hv3, wm,  acc[3][4]);
        }
    }
#pragma unroll
    for (int i = 0; i < 4; ++i) {
        size_t base = (size_t)(nb0 + wv * 4 + i) * 64 + lane;
        Q[base]  = acc[i][0];
        K[base]  = acc[i][1];
        V[base]  = acc[i][2];
        S[base]  = acc[i][3];
        QW[base] = acc[i][4];
    }
}

// ---------------- per-node online-softmax attention + relu + pool ----------------
// block=256 (4 waves), one node per wave; grid = 12500 exact

__global__ __launch_bounds__(256) void k_attn(const float* __restrict__ Q,
                                              const float* __restrict__ K,
                                              const float* __restrict__ V,
                                              const float* __restrict__ S,
                                              const float* __restrict__ QW,
                                              const float* __restrict__ Wel,
                                              const int* __restrict__ srcv,
                                              const float* __restrict__ eattr,
                                              const int* __restrict__ deg,
                                              const int* __restrict__ table,
                                              const int* __restrict__ batch,
                                              const float* __restrict__ inv,
                                              float* __restrict__ Hout,
                                              float* __restrict__ hcat,
                                              int layer) {
    __shared__ float we[16 * 64];   // 4 KB
    int tid = threadIdx.x;
    for (int i = tid; i < 1024; i += 256) we[i] = Wel[i];
    __syncthreads();

    int lane = tid & 63;
    int n = blockIdx.x * 4 + (tid >> 6);
    if (n >= NN) return;

    int dd = lane & 15;     // attr index within head
    int hg = lane >> 4;     // head

    float q  = Q[(size_t)n * 64 + lane];
    float qw = QW[(size_t)n * 64 + lane];
    int dg = deg[n];
    if (dg > MAXDEG) dg = MAXDEG;
    const int* tb = table + (size_t)n * MAXDEG;

    float m = -INFINITY, s = 0.f, av = 0.f, aa = 0.f;

    // software pipeline: values for edge i resident; indices for edge i+1 resident
    int e0  = (dg > 0) ? tb[0] : 0;
    int sn0 = (dg > 0) ? srcv[e0] : 0;
    float at0 = eattr[(size_t)e0 * 16 + dd];
    float kk0 = K[(size_t)sn0 * 64 + lane];
    float vv0 = V[(size_t)sn0 * 64 + lane];
    int e1  = (dg > 1) ? tb[1] : 0;
    int sn1 = (dg > 1) ? srcv[e1] : 0;

    for (int i = 0; i < dg; ++i) {
        // issue next-edge value gathers (independent of this iteration's chain)
        float at1 = eattr[(size_t)e1 * 16 + dd];
        float kk1 = K[(size_t)sn1 * 64 + lane];
        float vv1 = V[(size_t)sn1 * 64 + lane];
        int e2  = (i + 2 < dg) ? tb[i + 2] : 0;
        int sn2 = (i + 2 < dg) ? srcv[e2] : 0;

        float p = fmaf(q, kk0, qw * at0);
        p += __shfl_xor(p, 1, 16);
        p += __shfl_xor(p, 2, 16);
        p += __shfl_xor(p, 4, 16);
        p += __shfl_xor(p, 8, 16);
        float logit = p * ATT_SCALE;
        float mn = fmaxf(m, logit);
        float wold = __expf(m - mn);     // m=-inf first iter -> 0
        float a = __expf(logit - mn);
        s  = fmaf(s, wold, a);
        av = fmaf(av, wold, a * vv0);
        aa = fmaf(aa, wold, a * at0);
        m = mn;

        at0 = at1; kk0 = kk1; vv0 = vv1;
        e1 = e2; sn1 = sn2;
    }

    float rden = 1.0f / (s + 1e-16f);
    float eagg = 0.f;
#pragma unroll
    for (int j = 0; j < 16; ++j) {
        float aj = __shfl(aa, hg * 16 + j, 64);
        eagg = fmaf(aj, we[j * 64 + lane], eagg);
    }
    float agg = (av + eagg) * rden;
    float hn = fmaxf(agg + S[(size_t)n * 64 + lane], 0.f);
    Hout[(size_t)n * 64 + lane] = hn;

    int g = batch[n];
    atomicAdd(&hcat[g * 320 + layer * 64 + lane], hn * inv[g]);
}

// ---------------- final MLP: one block per graph ----------------

__global__ __launch_bounds__(256) void k_mlp(const float* __restrict__ hcat,
                                             const float* __restrict__ W1,
                                             const float* __restrict__ b1,
                                             const float* __restrict__ W2,
                                             const float* __restrict__ b2,
                                             float* __restrict__ out) {
    __shared__ float hc[320];
    __shared__ float red[256];
    int g = blockIdx.x, tid = threadIdx.x;
    for (int i = tid; i < 320; i += 256) hc[i] = hcat[g * 320 + i];
    __syncthreads();
    float part = 0.f;
    for (int j = tid; j < 320; j += 256) {
        float t = b1[j];
        for (int k = 0; k < 320; ++k) t = fmaf(hc[k], W1[k * 320 + j], t);
        part = fmaf(fmaxf(t, 0.f), W2[j], part);
    }
    red[tid] = part;
    __syncthreads();
    for (int off = 128; off > 0; off >>= 1) {
        if (tid < off) red[tid] += red[tid + off];
        __syncthreads();
    }
    if (tid == 0) out[g] = red[0] + b2[0];
}

// ---------------- launch ----------------

extern "C" void kernel_launch(void* const* d_in, const int* in_sizes, int n_in,
                              void* d_out, int out_size, void* d_ws, size_t ws_size,
                              hipStream_t stream) {
    const float* x     = (const float*)d_in[0];
    const int*   ei    = (const int*)d_in[1];     // [2,E]: src then dst
    const float* eattr = (const float*)d_in[2];
    const int*   batch = (const int*)d_in[3];
    const float* Wq    = (const float*)d_in[4];
    const float* Wk    = (const float*)d_in[5];
    const float* Wv    = (const float*)d_in[6];
    const float* We    = (const float*)d_in[7];
    const float* Wsk   = (const float*)d_in[8];
    const float* W1    = (const float*)d_in[9];
    const float* b1    = (const float*)d_in[10];
    const float* W2    = (const float*)d_in[11];
    const float* b2    = (const float*)d_in[12];
    float* out = (float*)d_out;

    // workspace carve (floats)
    float* ws = (float*)d_ws;
    size_t o = 0;
    float* Q    = ws + o; o += (size_t)NN * 64;
    float* K    = ws + o; o += (size_t)NN * 64;
    float* V    = ws + o; o += (size_t)NN * 64;
    float* S    = ws + o; o += (size_t)NN * 64;
    float* QW   = ws + o; o += (size_t)NN * 64;
    float* Hb   = ws + o; o += (size_t)NN * 64;
    float* Mw   = ws + o; o += 5 * 4096;
    float* inv  = ws + o; o += GG;
    float* hcat = ws + o; o += GG * 320;       // zeroed
    int*   deg  = (int*)(ws + o); o += NN;     // zeroed (contiguous with hcat)
    int*   table = (int*)(ws + o); o += (size_t)NN * MAXDEG;

    size_t zbytes = (size_t)(GG * 320 + NN) * 4;
    hipMemsetAsync(hcat, 0, zbytes, stream);

    k_bounds<<<1, 64, 0, stream>>>(batch, inv);
    k_table<<<(NE + 255) / 256, 256, 0, stream>>>(ei + NE, deg, table);
    k_M<<<(5 * 4096 + 255) / 256, 256, 0, stream>>>(Wq, We, Mw);

    const float* hsrc = x;
    for (int l = 0; l < 5; ++l) {
        k_proj<<<3125, 256, 0, stream>>>(hsrc,
                                         Wq + l * 4096, Wk + l * 4096,
                                         Wv + l * 4096, Wsk + l * 4096,
                                         Mw + l * 4096,
                                         Q, K, V, S, QW);
        k_attn<<<12500, 256, 0, stream>>>(Q, K, V, S, QW,
                                          We + l * 1024,
                                          ei, eattr, deg, table,
                                          batch, inv, Hb, hcat, l);
        hsrc = Hb;
    }
    k_mlp<<<GG, 256, 0, stream>>>(hcat, W1, b1, W2, b2, out);
}